// Round 17
// baseline (850.560 us; speedup 1.0000x reference)
//
#include <hip/hip_runtime.h>
#include <hip/hip_bf16.h>
#include <cstdint>
#include <cstddef>

typedef __attribute__((ext_vector_type(8))) short short8;   // 8 x bf16 (4 VGPRs)
typedef __attribute__((ext_vector_type(4))) float f32x4;    // MFMA accumulator

#define DEV static __device__ __forceinline__

constexpr int kS = 1024, kD = 2048, kH = 16, kHD = 128, kF = 8192;
constexpr int kM = 4096;            // B*S rows
constexpr int kDQKV = 6144;         // row-major QKV width
constexpr float kEPS = 1e-5f;

// ---------------- workspace layout (bytes) ----------------
constexpr size_t SZ_DD   = (size_t)kD * kD * 2;    // 8 MB   bf16 DxD weight
constexpr size_t SZ_FD   = (size_t)kF * kD * 2;    // 32 MB  bf16 FxD weight
constexpr size_t SZ_MD16 = (size_t)kM * kD * 2;    // 16 MB  bf16 activation
constexpr size_t SZ_MD32 = (size_t)kM * kD * 4;    // 32 MB  f32 activation
constexpr size_t OFF_WQ  = 0;                      // wq..wo2,x contiguous bf16 region
constexpr size_t OFF_WK  = OFF_WQ + SZ_DD;
constexpr size_t OFF_WV  = OFF_WK + SZ_DD;
constexpr size_t OFF_WO  = OFF_WV + SZ_DD;
constexpr size_t OFF_WI  = OFF_WO + SZ_DD;
constexpr size_t OFF_WO2 = OFF_WI + SZ_FD;
constexpr size_t OFF_XB  = OFF_WO2 + SZ_FD;        // region reused for h later
constexpr size_t OFF_Q   = OFF_XB + SZ_MD16;       // row-major QKV [4096][6144] bf16 (48MB)
constexpr size_t OFF_H   = OFF_XB;                 // 64 MB: xb+qkv dead by FFN1
constexpr size_t OFF_CTX = OFF_Q + 3 * SZ_MD16;
constexpr size_t OFF_Y1  = OFF_CTX + SZ_MD16;      // (unused, kept for layout stability)
constexpr size_t OFF_A1B = OFF_Y1 + SZ_MD32;       // bf16 attn_out (LN1 output)
constexpr size_t OFF_Y2  = OFF_A1B + SZ_MD16;      // Wo bf16 partials (2x16MB); bqkv early
constexpr size_t WS_NEED = OFF_Y2 + SZ_MD32;       // 256 MB total
// FFN2 bf16 partials (2x16MB) reuse dead wq..wo region at OFF_WQ.

DEV void gload16(const void* g, void* l) {
  __builtin_amdgcn_global_load_lds(
      (const __attribute__((address_space(1))) unsigned int*)g,
      (__attribute__((address_space(3))) unsigned int*)l, 16, 0, 0);
}

DEV float b2f(short s) {
  union { unsigned u; float f; } x;
  x.u = ((unsigned)(unsigned short)s) << 16;
  return x.f;
}

// ------------- fp32->bf16 convert: wq,wk,wv + x + bias concat -------------
// wo/wi/wo2 conversions live INSIDE attn_fwd (overlap its latency slack).
// Dest ushort4 indices: wq..wv -> [0,3M); x -> [12M,14M).
__global__ void cvt_all(const float* __restrict__ x,  const float* __restrict__ wq,
                        const float* __restrict__ wk, const float* __restrict__ wv,
                        const float* __restrict__ bq, const float* __restrict__ bk,
                        const float* __restrict__ bv,
                        __hip_bfloat16* __restrict__ outw, float* __restrict__ bqkv) {
  constexpr int M1 = 1 << 20;          // float4 count of one DxD matrix
  constexpr int NW = 5 * M1;           // 3 DxD weights + x (2M float4)
  int stride = gridDim.x * blockDim.x;
  for (int i = blockIdx.x * blockDim.x + threadIdx.x; i < NW + 1536; i += stride) {
    if (i < NW) {
      const float* src; int off; int dst;
      if (i < 3 * M1) { src = (i < M1) ? wq : (i < 2 * M1) ? wk : wv;
                        off = i & (M1 - 1); dst = i; }
      else            { src = x; off = i - 3 * M1; dst = i + 9 * M1; }
      float4 v = reinterpret_cast<const float4*>(src)[off];
      union { ushort4 u; __hip_bfloat16 h[4]; } o;
      o.h[0] = __float2bfloat16(v.x);
      o.h[1] = __float2bfloat16(v.y);
      o.h[2] = __float2bfloat16(v.z);
      o.h[3] = __float2bfloat16(v.w);
      reinterpret_cast<ushort4*>(outw)[dst] = o.u;
    } else {
      int j = i - NW;                   // 0..1535 (512 float4 per bias)
      const float* src = (j < 512) ? bq : (j < 1024) ? bk : bv;
      reinterpret_cast<float4*>(bqkv)[j] =
          reinterpret_cast<const float4*>(src)[j & 511];
    }
  }
}

// ------- 256x256 GEMM — 8-phase barrier-pair schedule (m201-style), clean epilogues -------
// BK=64, 8 waves 2x4 inside one 128x128 C-quadrant. Per phase: {ds_reads of
// tile t ; stage 1 half-tile of t+1 ; s_barrier ; lgkmcnt(0)+sched_barrier ;
// setprio(1) ; 16 MFMA ; setprio(0) ; [counted vmcnt(4)] ; s_barrier}.
// Quads q0(M0N0,A0B0) q1(M0N1,+B1) q2(M1N1,+A1) q3(M1N0,B0 re-read).
// Stage order A0',B0',B1',A1'; every waited half >=3 phases old (newest 2
// halves never drained — T4); tail waits 2/0/—/—. K-loop unrolled x2.
// MODE 0: out bf16 = acc + bias at [row*N+col] (row-major; QKV)
// MODE 2: out bf16 = gelu(acc + bias)
// MODE 3: bf16 partial (split-K): out0/out1 by split index
template <int MODE>
__global__ __launch_bounds__(512, 2)
void gemm256(const __hip_bfloat16* __restrict__ A,
             const __hip_bfloat16* __restrict__ Bt,
             const float* __restrict__ bias,
             __hip_bfloat16* __restrict__ out0, __hip_bfloat16* __restrict__ out1,
             void* __restrict__ outb,
             int M, int N, int K, int kLen) {
  __shared__ __align__(16) char lds[131072];   // A: [2][256][64]b16 @0, B: @65536
  const int tid = threadIdx.x;
  const int lane = tid & 63, w = tid >> 6;
  const int wm = w >> 2, wn = w & 3;           // 2x4 waves inside a 128x128 quadrant
  const int lg = lane >> 4, lr = lane & 15;
  const int gy = M >> 8, gx = N >> 8;
  const int nwg = gridDim.x, orig = blockIdx.x;
  const int l = (orig & 7) * (nwg >> 3) + (orig >> 3);   // XCD-chunked (nwg%8==0)
  const int tilesPer = gx * gy;
  const int spl = l / tilesPer;
  const int rem = l - spl * tilesPer;
  const int bx = rem / gy, by = rem - bx * gy;           // n-panel-major
  const int m0 = by * 256, n0 = bx * 256;
  const int k0 = spl * kLen;
  const int NT = kLen >> 6;

  const char* gs[8];
  #pragma unroll
  for (int h = 0; h < 4; ++h) {
    const __hip_bfloat16* src = (h < 2) ? A : Bt;
    const int r0 = ((h < 2) ? m0 : n0) + (h & 1) * 128;
    #pragma unroll
    for (int i = 0; i < 2; ++i) {
      int c = i * 512 + tid;
      int row = c >> 3, slot = c & 7;
      gs[h * 2 + i] =
          (const char*)(src + (size_t)(r0 + row) * K + k0 + (slot ^ (row & 7)) * 8);
    }
  }

#define STAGE(P, H, TOFF)                                                          \
  {                                                                                \
    char* dstb = lds + (((H) < 2) ? 0 : 65536) + (P) * 32768 + ((H) & 1) * 16384;  \
    gload16(gs[(H) * 2 + 0] + (TOFF) * 128, dstb + (0 * 512 + tid) * 16);          \
    gload16(gs[(H) * 2 + 1] + (TOFF) * 128, dstb + (1 * 512 + tid) * 16);          \
  }

  auto ldA = [&](int P, int qm, int mr, int kk) {
    int row = qm * 128 + wm * 64 + mr * 16 + lr;
    return *reinterpret_cast<const short8*>(
        lds + P * 32768 + row * 128 + (((kk * 4 + lg) ^ (row & 7)) * 16));
  };
  auto ldB = [&](int P, int qn, int nr, int kk) {
    int row = qn * 128 + wn * 32 + nr * 16 + lr;
    return *reinterpret_cast<const short8*>(
        lds + 65536 + P * 32768 + row * 128 + (((kk * 4 + lg) ^ (row & 7)) * 16));
  };

  f32x4 acc[4][4][2] = {};   // [phase-quad][mi][ni]

#define MFMA_QUAD(q, B)                                                         \
  _Pragma("unroll")                                                             \
  for (int kk = 0; kk < 2; ++kk)                                                \
    _Pragma("unroll")                                                           \
    for (int mi = 0; mi < 4; ++mi)                                              \
      _Pragma("unroll")                                                         \
      for (int ni = 0; ni < 2; ++ni)                                            \
        acc[q][mi][ni] = __builtin_amdgcn_mfma_f32_16x16x32_bf16(               \
            av[kk][mi], B[kk][ni], acc[q][mi][ni], 0, 0, 0);

#define VM(n) asm volatile("s_waitcnt vmcnt(" #n ")" ::: "memory");

#define PHASE_CORE(Q, B, WAITSTMT)                                              \
    __builtin_amdgcn_s_barrier();                                               \
    asm volatile("s_waitcnt lgkmcnt(0)" ::: "memory");                          \
    __builtin_amdgcn_sched_barrier(0);                                          \
    __builtin_amdgcn_s_setprio(1);                                              \
    MFMA_QUAD(Q, B)                                                             \
    __builtin_amdgcn_s_setprio(0);                                              \
    WAITSTMT                                                                    \
    __builtin_amdgcn_s_barrier();

#define TILE_BODY(P, PF)                                                        \
  {                                                                             \
    /* q0: read A0(8)+B0(4); stage A0' ; end-wait retires B1(t) */              \
    _Pragma("unroll")                                                           \
    for (int i = 0; i < 4; ++i) av[0][i] = ldA(P, 0, i, 0);                     \
    _Pragma("unroll")                                                           \
    for (int i = 0; i < 2; ++i) b0[0][i] = ldB(P, 0, i, 0);                     \
    _Pragma("unroll")                                                           \
    for (int i = 0; i < 4; ++i) av[1][i] = ldA(P, 0, i, 1);                     \
    _Pragma("unroll")                                                           \
    for (int i = 0; i < 2; ++i) b0[1][i] = ldB(P, 0, i, 1);                     \
    if (PF) STAGE((P) ^ 1, 0, 1 + (P))                                          \
    if (PF) { PHASE_CORE(0, b0, VM(4)) } else { PHASE_CORE(0, b0, VM(2)) }      \
    /* q1: read B1(4), reuse av(A0); stage B0' ; end-wait retires A1(t) */      \
    _Pragma("unroll")                                                           \
    for (int i = 0; i < 2; ++i) b1[0][i] = ldB(P, 1, i, 0);                     \
    _Pragma("unroll")                                                           \
    for (int i = 0; i < 2; ++i) b1[1][i] = ldB(P, 1, i, 1);                     \
    if (PF) STAGE((P) ^ 1, 2, 1 + (P))                                          \
    if (PF) { PHASE_CORE(1, b1, VM(4)) } else { PHASE_CORE(1, b1, VM(0)) }      \
    /* q2: read A1(8), reuse b1; stage B1' ; no end-wait */                     \
    _Pragma("unroll")                                                           \
    for (int i = 0; i < 4; ++i) av[0][i] = ldA(P, 1, i, 0);                     \
    _Pragma("unroll")                                                           \
    for (int i = 0; i < 4; ++i) av[1][i] = ldA(P, 1, i, 1);                     \
    if (PF) STAGE((P) ^ 1, 3, 1 + (P))                                          \
    PHASE_CORE(2, b1, )                                                         \
    /* q3: re-read B0(4), reuse av(A1); stage A1' ; end-wait retires A0',B0' */ \
    _Pragma("unroll")                                                           \
    for (int i = 0; i < 2; ++i) b0[0][i] = ldB(P, 0, i, 0);                     \
    _Pragma("unroll")                                                           \
    for (int i = 0; i < 2; ++i) b0[1][i] = ldB(P, 0, i, 1);                     \
    if (PF) STAGE((P) ^ 1, 1, 1 + (P))                                          \
    if (PF) { PHASE_CORE(3, b0, VM(4)) } else { PHASE_CORE(3, b0, ) }           \
  }

  // prologue: stage tile0 in order A0,B0,B1,A1; retire A0,B0 (q0's operands)
  STAGE(0, 0, 0) STAGE(0, 2, 0) STAGE(0, 3, 0) STAGE(0, 1, 0)
  VM(4)
  __builtin_amdgcn_s_barrier();

  for (int t2 = 0; t2 < NT; t2 += 2) {
    short8 av[2][4], b0[2][2], b1[2][2];
    TILE_BODY(0, true)
    TILE_BODY(1, (t2 + 2 < NT))
    #pragma unroll
    for (int j = 0; j < 8; ++j) gs[j] += 256;
  }
#undef TILE_BODY
#undef PHASE_CORE
#undef MFMA_QUAD
#undef VM
#undef STAGE

  // epilogue: q0=(0,0) q1=(0,1) q2=(1,1) q3=(1,0)
  #pragma unroll
  for (int p = 0; p < 4; ++p) {
    const int qm = (p >= 2) ? 1 : 0;
    const int qn = (p == 1 || p == 2) ? 1 : 0;
    #pragma unroll
    for (int ni = 0; ni < 2; ++ni) {
      int col = n0 + qn * 128 + wn * 32 + ni * 16 + lr;
      float bvv = 0.f;
      if constexpr (MODE != 3) bvv = bias[col];
      #pragma unroll
      for (int mi = 0; mi < 4; ++mi) {
        int row0 = m0 + qm * 128 + wm * 64 + mi * 16 + lg * 4;
        #pragma unroll
        for (int r = 0; r < 4; ++r) {
          int row = row0 + r;
          float val = acc[p][mi][ni][r] + bvv;
          if constexpr (MODE == 0) {
            ((__hip_bfloat16*)outb)[(size_t)row * N + col] = __float2bfloat16(val);
          } else if constexpr (MODE == 2) {
            float g = 0.5f * val * (1.0f + erff(val * 0.70710678118654752f));
            ((__hip_bfloat16*)outb)[(size_t)row * N + col] = __float2bfloat16(g);
          } else {
            __hip_bfloat16* o = spl ? out1 : out0;
            o[(size_t)row * N + col] = __float2bfloat16(val);
          }
        }
      }
    }
  }
}

// ------- flash attention — row-major QKV input; 2 q-tiles/block; wo/wi/wo2 cvt -------
__global__ __launch_bounds__(512, 2)
void attn_fwd(const __hip_bfloat16* __restrict__ qkv,
              const float* __restrict__ mask,
              __hip_bfloat16* __restrict__ ctx,
              const float* __restrict__ wo,
              const float* __restrict__ wi, const float* __restrict__ wo2,
              __hip_bfloat16* __restrict__ outw /* ushort4: wo@3M, wi@4M, wo2@8M */) {
  __shared__ __align__(16) char Ks[2][64 * 256];    // [buf][key][dim] slot16^(row&15)
  __shared__ __align__(16) char Vt[2][128 * 128];   // [buf][hd][key64] slot8^(hd&7)
  __shared__ __align__(16) char Ps[8][2048];        // per-wave P [16][64], ^((row&7)<<4)
  const int tid = threadIdx.x, lane = tid & 63, w = tid >> 6;
  const int lg = lane >> 4, lr = lane & 15;
  const int orig = blockIdx.x;                      // 256 blocks
  const int l = (orig & 7) * 32 + (orig >> 3);      // XCD-chunked: 8 bh per XCD
  const int qp = l & 3, bh = l >> 2;                // q-pair 0..3, bh 0..63
  const int b = bh >> 4, h = bh & 15;
  const int s4 = tid >> 5, hd4 = tid & 31;          // V-transpose role
  const size_t rb = (size_t)b * kS;                 // global row base
  const int hc = h * kHD;                           // head column offset

  short8 qf[2][4];
  #pragma unroll
  for (int s = 0; s < 2; ++s) {
    const __hip_bfloat16* qp_ =
        qkv + (rb + qp * 256 + s * 128 + w * 16 + lr) * kDQKV + hc + lg * 8;
    #pragma unroll
    for (int kk = 0; kk < 4; ++kk)
      qf[s][kk] = *reinterpret_cast<const short8*>(qp_ + kk * 32);
  }

  auto stageK = [&](int bufi, int t) {
    #pragma unroll
    for (int i = 0; i < 2; ++i) {                   // K tile: 64 rows x 256B
      int c = i * 512 + tid;
      int row = c >> 4, slot = c & 15;
      gload16(qkv + (rb + t * 64 + row) * kDQKV + kD + hc + (slot ^ (row & 15)) * 8,
              Ks[bufi] + c * 16);
    }
  };
  union VU { uint2 u; ushort s[4]; };
  VU vr[4];
  auto loadV = [&](int t) {
    #pragma unroll
    for (int i = 0; i < 4; ++i)
      vr[i].u = *reinterpret_cast<const uint2*>(
          qkv + (rb + t * 64 + s4 * 4 + i) * kDQKV + 2 * kD + hc + hd4 * 4);
  };
  auto writeV = [&](int bufi) {
    #pragma unroll
    for (int j = 0; j < 4; ++j) {
      int hd = hd4 * 4 + j;
      ushort4 o4;
      o4.x = vr[0].s[j]; o4.y = vr[1].s[j]; o4.z = vr[2].s[j]; o4.w = vr[3].s[j];
      *reinterpret_cast<ushort4*>(
          Vt[bufi] + hd * 128 + (((s4 >> 1) ^ (hd & 7)) << 4) + ((s4 & 1) << 3)) = o4;
    }
  };
  // interleaved weight conversion: 4 float4 (wi|wo2) + up to 1 float4 (wo) per slot
  float4 cw[4]; float4 cwo;
  auto cvLoad = [&](int t) {
    int g0 = ((orig * 16 + t) * 512 + tid) * 4;     // 0..8M-4
    #pragma unroll
    for (int j = 0; j < 4; ++j) {
      int g = g0 + j;
      const float* src = (g < (4 << 20)) ? wi : wo2;
      int off = g & ((4 << 20) - 1);
      cw[j] = reinterpret_cast<const float4*>(src)[off];
    }
    int slot = (orig * 16 + t) * 512 + tid;         // 0..2M-1
    if (slot < (1 << 20)) cwo = reinterpret_cast<const float4*>(wo)[slot];
  };
  auto cvStore = [&](int t) {
    int g0 = ((orig * 16 + t) * 512 + tid) * 4;
    #pragma unroll
    for (int j = 0; j < 4; ++j) {
      union { ushort4 u; __hip_bfloat16 hh[4]; } o4;
      o4.hh[0] = __float2bfloat16(cw[j].x);
      o4.hh[1] = __float2bfloat16(cw[j].y);
      o4.hh[2] = __float2bfloat16(cw[j].z);
      o4.hh[3] = __float2bfloat16(cw[j].w);
      reinterpret_cast<ushort4*>(outw)[(4 << 20) + g0 + j] = o4.u;
    }
    int slot = (orig * 16 + t) * 512 + tid;
    if (slot < (1 << 20)) {
      union { ushort4 u; __hip_bfloat16 hh[4]; } o4;
      o4.hh[0] = __float2bfloat16(cwo.x);
      o4.hh[1] = __float2bfloat16(cwo.y);
      o4.hh[2] = __float2bfloat16(cwo.z);
      o4.hh[3] = __float2bfloat16(cwo.w);
      reinterpret_cast<ushort4*>(outw)[(3 << 20) + slot] = o4.u;
    }
  };

  f32x4 o[2][8] = {};
  float mrun[2][4], lrun[2][4];
  #pragma unroll
  for (int s = 0; s < 2; ++s)
    #pragma unroll
    for (int r = 0; r < 4; ++r) { mrun[s][r] = -1e30f; lrun[s][r] = 0.f; }
  const float scale = 0.08838834764831845f;         // 1/sqrt(128)

  stageK(0, 0);
  loadV(0);
  writeV(0);
  __syncthreads();

  int buf = 0;
  for (int t = 0; t < 16; ++t) {
    if (t + 1 < 16) { stageK(buf ^ 1, t + 1); loadV(t + 1); }
    cvLoad(t);                                      // fp32 weight chunk in flight

    float mv[4];
    #pragma unroll
    for (int j = 0; j < 4; ++j) mv[j] = mask[(size_t)b * kS + t * 64 + j * 16 + lr];

    #pragma unroll
    for (int s = 0; s < 2; ++s) {
      f32x4 sacc[4] = {};
      #pragma unroll
      for (int j = 0; j < 4; ++j) {
        int key = j * 16 + lr;
        #pragma unroll
        for (int kk = 0; kk < 4; ++kk) {
          short8 bfrag = *reinterpret_cast<const short8*>(
              Ks[buf] + key * 256 + (((kk * 4 + lg) ^ (key & 15)) * 16));
          sacc[j] = __builtin_amdgcn_mfma_f32_16x16x32_bf16(qf[s][kk], bfrag, sacc[j], 0, 0, 0);
        }
      }
      float sarr[4][4];
      #pragma unroll
      for (int j = 0; j < 4; ++j)
        #pragma unroll
        for (int r = 0; r < 4; ++r) sarr[j][r] = sacc[j][r] * scale + mv[j];
      #pragma unroll
      for (int r = 0; r < 4; ++r) {
        float tm = fmaxf(fmaxf(sarr[0][r], sarr[1][r]), fmaxf(sarr[2][r], sarr[3][r]));
        #pragma unroll
        for (int d = 1; d < 16; d <<= 1) tm = fmaxf(tm, __shfl_xor(tm, d));
        float mnew = fmaxf(mrun[s][r], tm);
        float alpha = __expf(mrun[s][r] - mnew);
        mrun[s][r] = mnew;
        float rs = 0.f;
        #pragma unroll
        for (int j = 0; j < 4; ++j) {
          float p = __expf(sarr[j][r] - mnew);
          sarr[j][r] = p;
          rs += p;
        }
        #pragma unroll
        for (int d = 1; d < 16; d <<= 1) rs += __shfl_xor(rs, d);
        lrun[s][r] = lrun[s][r] * alpha + rs;
        #pragma unroll
        for (int n = 0; n < 8; ++n) o[s][n][r] *= alpha;
      }
      #pragma unroll
      for (int r = 0; r < 4; ++r) {
        int qr = lg * 4 + r;
        #pragma unroll
        for (int j = 0; j < 4; ++j)
          *reinterpret_cast<__hip_bfloat16*>(
              Ps[w] + ((qr * 128 + (j * 16 + lr) * 2) ^ ((qr & 7) << 4))) =
              __float2bfloat16(sarr[j][r]);
      }
      #pragma unroll
      for (int kk2 = 0; kk2 < 2; ++kk2) {
        short8 pa = *reinterpret_cast<const short8*>(
            Ps[w] + ((lr * 128 + kk2 * 64 + lg * 16) ^ ((lr & 7) << 4)));
        #pragma unroll
        for (int n = 0; n < 8; ++n) {
          int hd = n * 16 + lr;
          short8 vb = *reinterpret_cast<const short8*>(
              Vt[buf] + hd * 128 + (((kk2 * 4 + lg) ^ (hd & 7)) * 16));
          o[s][n] = __builtin_amdgcn_mfma_f32_16x16x32_bf16(pa, vb, o[s][n], 0, 0, 0);
        }
      }
    }
    cvStore(t);                                     // convert + store (auto-waits cw)
    if (t + 1 < 16) writeV(buf ^ 1);
    __syncthreads();
    buf ^= 1;
  }

  #pragma unroll
  for (int s = 0; s < 2; ++s)
    #pragma unroll
    for (int r = 0; r < 4; ++r) {
      float inv = 1.0f / lrun[s][r];
      int srow = qp * 256 + s * 128 + w * 16 + lg * 4 + r;
      __hip_bfloat16* cp = ctx + (rb + srow) * kD + hc + lr;
      #pragma unroll
      for (int n = 0; n < 8; ++n) cp[n * 16] = __float2bfloat16(o[s][n][r] * inv);
    }
}

// -- LayerNorm over (bf16 p0 + bf16 p1 + f32 bias + bf16 res), one 2048-row/block --
// F32OUT=false: write bf16 only (LN1 -> a1b). F32OUT=true: write f32 (LN2 -> d_out).
template <bool F32OUT>
__global__ void ln_fuse(const __hip_bfloat16* __restrict__ p0,
                        const __hip_bfloat16* __restrict__ p1,
                        const float* __restrict__ bias,
                        const __hip_bfloat16* __restrict__ res,
                        const float* __restrict__ w, const float* __restrict__ b,
                        float* __restrict__ outf, __hip_bfloat16* __restrict__ outb) {
  const int row = blockIdx.x, tid = threadIdx.x;
  const size_t base = (size_t)row * kD;
  short8 a = reinterpret_cast<const short8*>(p0 + base)[tid];
  short8 c = reinterpret_cast<const short8*>(p1 + base)[tid];
  short8 rr = reinterpret_cast<const short8*>(res + base)[tid];
  float v[8];
  #pragma unroll
  for (int i = 0; i < 2; ++i) {
    int c4 = tid * 2 + i;
    float4 bs = reinterpret_cast<const float4*>(bias)[c4];
    v[i * 4 + 0] = b2f(a[i * 4 + 0]) + b2f(c[i * 4 + 0]) + b2f(rr[i * 4 + 0]) + bs.x;
    v[i * 4 + 1] = b2f(a[i * 4 + 1]) + b2f(c[i * 4 + 1]) + b2f(rr[i * 4 + 1]) + bs.y;
    v[i * 4 + 2] = b2f(a[i * 4 + 2]) + b2f(c[i * 4 + 2]) + b2f(rr[i * 4 + 2]) + bs.z;
    v[i * 4 + 3] = b2f(a[i * 4 + 3]) + b2f(c[i * 4 + 3]) + b2f(rr[i * 4 + 3]) + bs.w;
  }
  float s = 0.f;
  #pragma unroll
  for (int i = 0; i < 8; ++i) s += v[i];
  #pragma unroll
  for (int off = 32; off > 0; off >>= 1) s += __shfl_down(s, off);
  __shared__ float r1[4], r2[4];
  if ((tid & 63) == 0) r1[tid >> 6] = s;
  __syncthreads();
  float mean = (r1[0] + r1[1] + r1[2] + r1[3]) * (1.0f / kD);
  float qv = 0.f;
  #pragma unroll
  for (int i = 0; i < 8; ++i) { float d = v[i] - mean; qv += d * d; }
  #pragma unroll
  for (int off = 32; off > 0; off >>= 1) qv += __shfl_down(qv, off);
  if ((tid & 63) == 0) r2[tid >> 6] = qv;
  __syncthreads();
  float rstd = rsqrtf((r2[0] + r2[1] + r2[2] + r2[3]) * (1.0f / kD) + kEPS);
  #pragma unroll
  for (int i = 0; i < 8; ++i) {
    int col = tid * 8 + i;
    float ov = (v[i] - mean) * rstd * w[col] + b[col];
    if constexpr (F32OUT) outf[base + col] = ov;
    else                  outb[base + col] = __float2bfloat16(ov);
  }
}

// ---------------- launcher ----------------
extern "C" void kernel_launch(void* const* d_in, const int* in_sizes, int n_in,
                              void* d_out, int out_size, void* d_ws, size_t ws_size,
                              hipStream_t stream) {
  (void)in_sizes; (void)n_in; (void)out_size;
  if (ws_size < WS_NEED) return;
  const float* x    = (const float*)d_in[0];
  const float* mask = (const float*)d_in[1];
  const float* wq   = (const float*)d_in[2];
  const float* bq   = (const float*)d_in[3];
  const float* wk   = (const float*)d_in[4];
  const float* bk   = (const float*)d_in[5];
  const float* wv   = (const float*)d_in[6];
  const float* bv   = (const float*)d_in[7];
  const float* wo   = (const float*)d_in[8];
  const float* bo   = (const float*)d_in[9];
  const float* l1w  = (const float*)d_in[10];
  const float* l1b  = (const float*)d_in[11];
  const float* wi   = (const float*)d_in[12];
  const float* bi   = (const float*)d_in[13];
  const float* wo2  = (const float*)d_in[14];
  const float* bo2  = (const float*)d_in[15];
  const float* l2w  = (const float*)d_in[16];
  const float* l2b  = (const float*)d_in[17];

  char* ws = (char*)d_ws;
  __hip_bfloat16* wqb  = (__hip_bfloat16*)(ws + OFF_WQ);
  __hip_bfloat16* wob  = (__hip_bfloat16*)(ws + OFF_WO);
  __hip_bfloat16* wib  = (__hip_bfloat16*)(ws + OFF_WI);
  __hip_bfloat16* wo2b = (__hip_bfloat16*)(ws + OFF_WO2);
  __hip_bfloat16* xb   = (__hip_bfloat16*)(ws + OFF_XB);
  __hip_bfloat16* qkvb = (__hip_bfloat16*)(ws + OFF_Q);    // [4096][6144]
  __hip_bfloat16* hb   = (__hip_bfloat16*)(ws + OFF_H);
  __hip_bfloat16* ctxb = (__hip_bfloat16*)(ws + OFF_CTX);
  __hip_bfloat16* a1b  = (__hip_bfloat16*)(ws + OFF_A1B);  // bf16 attn_out (LN1 out)
  __hip_bfloat16* wp0 = (__hip_bfloat16*)(ws + OFF_Y2);            // Wo partial 0
  __hip_bfloat16* wp1 = (__hip_bfloat16*)(ws + OFF_Y2 + SZ_MD16);  // Wo partial 1
  __hip_bfloat16* fp0 = (__hip_bfloat16*)(ws + OFF_WQ);            // FFN2 partial 0
  __hip_bfloat16* fp1 = (__hip_bfloat16*)(ws + OFF_WQ + SZ_MD16);  // FFN2 partial 1
  float* bqkv = (float*)(ws + OFF_Y2);   // 24KB concat bias; dead before Wo partials

  // conversions: x + wq/wk/wv + bias concat (wo/wi/wo2 handled inside attn)
  cvt_all<<<2048, 256, 0, stream>>>(x, wq, wk, wv, bq, bk, bv, wqb, bqkv);

  dim3 blk(512);
  // fused QKV projection: M=4096, N=6144, K=2048 -> grid 384, row-major out
  gemm256<0><<<dim3(384), blk, 0, stream>>>(
      xb, wqb, bqkv, nullptr, nullptr, qkvb, kM, kDQKV, kD, kD);
  // attention (256 blocks, 2 q-tiles each) + wo/wi/wo2 conversion
  attn_fwd<<<dim3(256), dim3(512), 0, stream>>>(qkvb, mask, ctxb, wo, wi, wo2, wqb);
  // out proj, split-K x2 (grid 256), bf16 partials wp0,wp1; LN1 fuses +bo+xb -> a1b
  gemm256<3><<<dim3(256), blk, 0, stream>>>(
      ctxb, wob, nullptr, wp0, wp1, nullptr, kM, kD, kD, kD / 2);
  ln_fuse<false><<<kM, 256, 0, stream>>>(wp0, wp1, bo, xb, l1w, l1b, nullptr, a1b);
  // FFN1: grid 32*16 = 512, GELU epilogue
  gemm256<2><<<dim3(512), blk, 0, stream>>>(
      a1b, wib, bi, nullptr, nullptr, hb, kM, kF, kD, kD);
  // FFN2: split-K x2 (grid 256), bf16 partials fp0,fp1; LN2 fuses +bo2+a1b -> d_out
  gemm256<3><<<dim3(256), blk, 0, stream>>>(
      hb, wo2b, nullptr, fp0, fp1, nullptr, kM, kD, kF, kF / 2);
  ln_fuse<true><<<kM, 256, 0, stream>>>(fp0, fp1, bo2, a1b, l2w, l2b, (float*)d_out, nullptr);
}

// Round 18
// 555.801 us; speedup vs baseline: 1.5303x; 1.5303x over previous
//
#include <hip/hip_runtime.h>
#include <hip/hip_bf16.h>
#include <cstdint>
#include <cstddef>

typedef __attribute__((ext_vector_type(8))) short short8;   // 8 x bf16 (4 VGPRs)
typedef __attribute__((ext_vector_type(4))) float f32x4;    // MFMA accumulator

#define DEV static __device__ __forceinline__

constexpr int kS = 1024, kD = 2048, kH = 16, kHD = 128, kF = 8192;
constexpr int kM = 4096;            // B*S rows
constexpr int kDQKV = 6144;         // row-major QKV width
constexpr float kEPS = 1e-5f;

// ---------------- workspace layout (bytes) ----------------
constexpr size_t SZ_DD   = (size_t)kD * kD * 2;    // 8 MB   bf16 DxD weight
constexpr size_t SZ_FD   = (size_t)kF * kD * 2;    // 32 MB  bf16 FxD weight
constexpr size_t SZ_MD16 = (size_t)kM * kD * 2;    // 16 MB  bf16 activation
constexpr size_t SZ_MD32 = (size_t)kM * kD * 4;    // 32 MB  f32 activation
constexpr size_t OFF_WQ  = 0;                      // wq..wo2,x contiguous bf16 region
constexpr size_t OFF_WK  = OFF_WQ + SZ_DD;
constexpr size_t OFF_WV  = OFF_WK + SZ_DD;
constexpr size_t OFF_WO  = OFF_WV + SZ_DD;
constexpr size_t OFF_WI  = OFF_WO + SZ_DD;
constexpr size_t OFF_WO2 = OFF_WI + SZ_FD;
constexpr size_t OFF_XB  = OFF_WO2 + SZ_FD;        // region reused for h later
constexpr size_t OFF_Q   = OFF_XB + SZ_MD16;       // row-major QKV [4096][6144] bf16 (48MB)
constexpr size_t OFF_H   = OFF_XB;                 // 64 MB: xb+qkv dead by FFN1
constexpr size_t OFF_CTX = OFF_Q + 3 * SZ_MD16;
constexpr size_t OFF_Y1  = OFF_CTX + SZ_MD16;      // (unused, kept for layout stability)
constexpr size_t OFF_A1B = OFF_Y1 + SZ_MD32;       // bf16 attn_out (LN1 output)
constexpr size_t OFF_Y2  = OFF_A1B + SZ_MD16;      // Wo bf16 partials (2x16MB); bqkv early
constexpr size_t WS_NEED = OFF_Y2 + SZ_MD32;       // 256 MB total
// FFN2 bf16 partials (2x16MB) reuse dead wq..wo region at OFF_WQ.

DEV void gload16(const void* g, void* l) {
  __builtin_amdgcn_global_load_lds(
      (const __attribute__((address_space(1))) unsigned int*)g,
      (__attribute__((address_space(3))) unsigned int*)l, 16, 0, 0);
}

DEV float b2f(short s) {
  union { unsigned u; float f; } x;
  x.u = ((unsigned)(unsigned short)s) << 16;
  return x.f;
}

// ------------- fp32->bf16 convert: wq,wk,wv + x + bias concat -------------
// wo/wi/wo2 conversions live INSIDE attn_fwd (overlap its latency slack).
// Dest ushort4 indices: wq..wv -> [0,3M); x -> [12M,14M).
__global__ void cvt_all(const float* __restrict__ x,  const float* __restrict__ wq,
                        const float* __restrict__ wk, const float* __restrict__ wv,
                        const float* __restrict__ bq, const float* __restrict__ bk,
                        const float* __restrict__ bv,
                        __hip_bfloat16* __restrict__ outw, float* __restrict__ bqkv) {
  constexpr int M1 = 1 << 20;          // float4 count of one DxD matrix
  constexpr int NW = 5 * M1;           // 3 DxD weights + x (2M float4)
  int stride = gridDim.x * blockDim.x;
  for (int i = blockIdx.x * blockDim.x + threadIdx.x; i < NW + 1536; i += stride) {
    if (i < NW) {
      const float* src; int off; int dst;
      if (i < 3 * M1) { src = (i < M1) ? wq : (i < 2 * M1) ? wk : wv;
                        off = i & (M1 - 1); dst = i; }
      else            { src = x; off = i - 3 * M1; dst = i + 9 * M1; }
      float4 v = reinterpret_cast<const float4*>(src)[off];
      union { ushort4 u; __hip_bfloat16 h[4]; } o;
      o.h[0] = __float2bfloat16(v.x);
      o.h[1] = __float2bfloat16(v.y);
      o.h[2] = __float2bfloat16(v.z);
      o.h[3] = __float2bfloat16(v.w);
      reinterpret_cast<ushort4*>(outw)[dst] = o.u;
    } else {
      int j = i - NW;                   // 0..1535 (512 float4 per bias)
      const float* src = (j < 512) ? bq : (j < 1024) ? bk : bv;
      reinterpret_cast<float4*>(bqkv)[j] =
          reinterpret_cast<const float4*>(src)[j & 511];
    }
  }
}

// ---------------- 256x256 GEMM (r8/r11 schedule — frozen) ----------------
// MODE 0: out bf16 = acc + bias at [row*N+col] (plain row-major; used for QKV)
// MODE 2: out bf16 = gelu(acc + bias) at [row*N+col]
// MODE 3: bf16 partial (split-K): out0/out1 selected by split index
template <int MODE>
__global__ __launch_bounds__(512, 2)
void gemm256(const __hip_bfloat16* __restrict__ A,
             const __hip_bfloat16* __restrict__ Bt,
             const float* __restrict__ bias,
             __hip_bfloat16* __restrict__ out0, __hip_bfloat16* __restrict__ out1,
             void* __restrict__ outb,
             int M, int N, int K, int kLen) {
  __shared__ __align__(16) char lds[131072];   // A: [2][256][64]b16 @0, B: @65536
  const int tid = threadIdx.x;
  const int lane = tid & 63, w = tid >> 6;
  const int wm = w >> 2, wn = w & 3;
  const int hw = w >> 2;
  const int lg = lane >> 4, lr = lane & 15;
  const int gy = M >> 8, gx = N >> 8;
  const int nwg = gridDim.x, orig = blockIdx.x;
  const int l = (orig & 7) * (nwg >> 3) + (orig >> 3);   // XCD-chunked (nwg%8==0)
  const int tilesPer = gx * gy;
  const int spl = l / tilesPer;
  const int rem = l - spl * tilesPer;
  const int bx = rem / gy, by = rem - bx * gy;           // n-panel-major
  const int m0 = by * 256, n0 = bx * 256;
  const int k0 = spl * kLen;
  const int NT = kLen >> 6;

  const char* gs[8];
  #pragma unroll
  for (int h = 0; h < 4; ++h) {
    const __hip_bfloat16* src = (h < 2) ? A : Bt;
    const int r0 = ((h < 2) ? m0 : n0) + (h & 1) * 128;
    #pragma unroll
    for (int i = 0; i < 2; ++i) {
      int c = i * 512 + tid;
      int row = c >> 3, slot = c & 7;
      gs[h * 2 + i] =
          (const char*)(src + (size_t)(r0 + row) * K + k0 + (slot ^ (row & 7)) * 8);
    }
  }

#define STAGE(P, H, TOFF)                                                          \
  {                                                                                \
    char* dstb = lds + (((H) < 2) ? 0 : 65536) + (P) * 32768 + ((H) & 1) * 16384;  \
    gload16(gs[(H) * 2 + 0] + (TOFF) * 128, dstb + (0 * 512 + tid) * 16);          \
    gload16(gs[(H) * 2 + 1] + (TOFF) * 128, dstb + (1 * 512 + tid) * 16);          \
  }

  auto ldA = [&](int P, int qm, int mr, int kk) {
    int row = qm * 128 + wm * 64 + mr * 16 + lr;
    return *reinterpret_cast<const short8*>(
        lds + P * 32768 + row * 128 + (((kk * 4 + lg) ^ (row & 7)) * 16));
  };
  auto ldB = [&](int P, int qn, int nr, int kk) {
    int row = qn * 128 + wn * 32 + nr * 16 + lr;
    return *reinterpret_cast<const short8*>(
        lds + 65536 + P * 32768 + row * 128 + (((kk * 4 + lg) ^ (row & 7)) * 16));
  };

  f32x4 acc[4][4][2] = {};   // [phase][mi][ni]

#define MFMA_HALF(p, kk, B)                                                     \
  _Pragma("unroll")                                                             \
  for (int mi = 0; mi < 4; ++mi)                                                \
    _Pragma("unroll")                                                           \
    for (int ni = 0; ni < 2; ++ni)                                              \
      acc[p][mi][ni] = __builtin_amdgcn_mfma_f32_16x16x32_bf16(                 \
          av[kk][mi], B[kk][ni], acc[p][mi][ni], 0, 0, 0);

#define WAIT_LGKM(n)                                                            \
  asm volatile("s_waitcnt lgkmcnt(" #n ")" ::: "memory");                       \
  __builtin_amdgcn_sched_barrier(0);

#define TILE_BODY(P, PF)                                                        \
  {                                                                             \
    asm volatile("s_waitcnt vmcnt(0)" ::: "memory");                            \
    __builtin_amdgcn_s_barrier();                                               \
    _Pragma("unroll")                                                           \
    for (int i = 0; i < 4; ++i) av[0][i] = ldA(P, hw, i, 0);                    \
    _Pragma("unroll")                                                           \
    for (int i = 0; i < 2; ++i) b0[0][i] = ldB(P, hw, i, 0);                    \
    _Pragma("unroll")                                                           \
    for (int i = 0; i < 4; ++i) av[1][i] = ldA(P, hw, i, 1);                    \
    _Pragma("unroll")                                                           \
    for (int i = 0; i < 2; ++i) b0[1][i] = ldB(P, hw, i, 1);                    \
    if (PF) { STAGE((P) ^ 1, 0, 1 + (P)) STAGE((P) ^ 1, 2, 1 + (P)) }           \
    WAIT_LGKM(6)                                                                \
    __builtin_amdgcn_s_setprio(1);                                              \
    MFMA_HALF(0, 0, b0)                                                         \
    WAIT_LGKM(0)                                                                \
    MFMA_HALF(0, 1, b0)                                                         \
    __builtin_amdgcn_s_setprio(0);                                              \
    _Pragma("unroll")                                                           \
    for (int i = 0; i < 2; ++i) b1[0][i] = ldB(P, 1 - hw, i, 0);                \
    _Pragma("unroll")                                                           \
    for (int i = 0; i < 2; ++i) b1[1][i] = ldB(P, 1 - hw, i, 1);                \
    if (PF) { STAGE((P) ^ 1, 3, 1 + (P)) STAGE((P) ^ 1, 1, 1 + (P)) }           \
    WAIT_LGKM(2)                                                                \
    __builtin_amdgcn_s_setprio(1);                                              \
    MFMA_HALF(1, 0, b1)                                                         \
    WAIT_LGKM(0)                                                                \
    MFMA_HALF(1, 1, b1)                                                         \
    __builtin_amdgcn_s_setprio(0);                                              \
    _Pragma("unroll")                                                           \
    for (int i = 0; i < 4; ++i) av[0][i] = ldA(P, 1 - hw, i, 0);                \
    _Pragma("unroll")                                                           \
    for (int i = 0; i < 4; ++i) av[1][i] = ldA(P, 1 - hw, i, 1);                \
    WAIT_LGKM(4)                                                                \
    __builtin_amdgcn_s_setprio(1);                                              \
    MFMA_HALF(2, 0, b1)                                                         \
    WAIT_LGKM(0)                                                                \
    MFMA_HALF(2, 1, b1)                                                         \
    __builtin_amdgcn_s_setprio(0);                                              \
    _Pragma("unroll")                                                           \
    for (int i = 0; i < 2; ++i) b0[0][i] = ldB(P, hw, i, 0);                    \
    _Pragma("unroll")                                                           \
    for (int i = 0; i < 2; ++i) b0[1][i] = ldB(P, hw, i, 1);                    \
    WAIT_LGKM(2)                                                                \
    __builtin_amdgcn_s_setprio(1);                                              \
    MFMA_HALF(3, 0, b0)                                                         \
    WAIT_LGKM(0)                                                                \
    MFMA_HALF(3, 1, b0)                                                         \
    __builtin_amdgcn_s_setprio(0);                                              \
  }

  STAGE(0, 0, 0) STAGE(0, 2, 0) STAGE(0, 3, 0) STAGE(0, 1, 0)

  for (int t2 = 0; t2 < NT; t2 += 2) {
    short8 av[2][4], b0[2][2], b1[2][2];
    TILE_BODY(0, true)
    TILE_BODY(1, (t2 + 2 < NT))
    #pragma unroll
    for (int j = 0; j < 8; ++j) gs[j] += 256;
  }
#undef TILE_BODY
#undef MFMA_HALF
#undef WAIT_LGKM
#undef STAGE

  // epilogue: p0:(hw,hw) p1:(hw,1-hw) p2:(1-hw,1-hw) p3:(1-hw,hw)
  #pragma unroll
  for (int p = 0; p < 4; ++p) {
    const int qm = (p < 2) ? hw : 1 - hw;
    const int qn = (p == 0 || p == 3) ? hw : 1 - hw;
    #pragma unroll
    for (int ni = 0; ni < 2; ++ni) {
      int col = n0 + qn * 128 + wn * 32 + ni * 16 + lr;
      float bvv = 0.f;
      if constexpr (MODE != 3) bvv = bias[col];
      #pragma unroll
      for (int mi = 0; mi < 4; ++mi) {
        int row0 = m0 + qm * 128 + wm * 64 + mi * 16 + lg * 4;
        #pragma unroll
        for (int r = 0; r < 4; ++r) {
          int row = row0 + r;
          float val = acc[p][mi][ni][r] + bvv;
          if constexpr (MODE == 0) {
            ((__hip_bfloat16*)outb)[(size_t)row * N + col] = __float2bfloat16(val);
          } else if constexpr (MODE == 2) {
            float g = 0.5f * val * (1.0f + erff(val * 0.70710678118654752f));
            ((__hip_bfloat16*)outb)[(size_t)row * N + col] = __float2bfloat16(g);
          } else {
            __hip_bfloat16* o = spl ? out1 : out0;
            o[(size_t)row * N + col] = __float2bfloat16(val);
          }
        }
      }
    }
  }
}

// ------- flash attention — row-major QKV input; 2 q-tiles/block; wo/wi/wo2 cvt -------
__global__ __launch_bounds__(512, 2)
void attn_fwd(const __hip_bfloat16* __restrict__ qkv,
              const float* __restrict__ mask,
              __hip_bfloat16* __restrict__ ctx,
              const float* __restrict__ wo,
              const float* __restrict__ wi, const float* __restrict__ wo2,
              __hip_bfloat16* __restrict__ outw /* ushort4: wo@3M, wi@4M, wo2@8M */) {
  __shared__ __align__(16) char Ks[2][64 * 256];    // [buf][key][dim] slot16^(row&15)
  __shared__ __align__(16) char Vt[2][128 * 128];   // [buf][hd][key64] slot8^(hd&7)
  __shared__ __align__(16) char Ps[8][2048];        // per-wave P [16][64], ^((row&7)<<4)
  const int tid = threadIdx.x, lane = tid & 63, w = tid >> 6;
  const int lg = lane >> 4, lr = lane & 15;
  const int orig = blockIdx.x;                      // 256 blocks
  const int l = (orig & 7) * 32 + (orig >> 3);      // XCD-chunked: 8 bh per XCD
  const int qp = l & 3, bh = l >> 2;                // q-pair 0..3, bh 0..63
  const int b = bh >> 4, h = bh & 15;
  const int s4 = tid >> 5, hd4 = tid & 31;          // V-transpose role
  const size_t rb = (size_t)b * kS;                 // global row base
  const int hc = h * kHD;                           // head column offset

  short8 qf[2][4];
  #pragma unroll
  for (int s = 0; s < 2; ++s) {
    const __hip_bfloat16* qp_ =
        qkv + (rb + qp * 256 + s * 128 + w * 16 + lr) * kDQKV + hc + lg * 8;
    #pragma unroll
    for (int kk = 0; kk < 4; ++kk)
      qf[s][kk] = *reinterpret_cast<const short8*>(qp_ + kk * 32);
  }

  auto stageK = [&](int bufi, int t) {
    #pragma unroll
    for (int i = 0; i < 2; ++i) {                   // K tile: 64 rows x 256B
      int c = i * 512 + tid;
      int row = c >> 4, slot = c & 15;
      gload16(qkv + (rb + t * 64 + row) * kDQKV + kD + hc + (slot ^ (row & 15)) * 8,
              Ks[bufi] + c * 16);
    }
  };
  union VU { uint2 u; ushort s[4]; };
  VU vr[4];
  auto loadV = [&](int t) {
    #pragma unroll
    for (int i = 0; i < 4; ++i)
      vr[i].u = *reinterpret_cast<const uint2*>(
          qkv + (rb + t * 64 + s4 * 4 + i) * kDQKV + 2 * kD + hc + hd4 * 4);
  };
  auto writeV = [&](int bufi) {
    #pragma unroll
    for (int j = 0; j < 4; ++j) {
      int hd = hd4 * 4 + j;
      ushort4 o4;
      o4.x = vr[0].s[j]; o4.y = vr[1].s[j]; o4.z = vr[2].s[j]; o4.w = vr[3].s[j];
      *reinterpret_cast<ushort4*>(
          Vt[bufi] + hd * 128 + (((s4 >> 1) ^ (hd & 7)) << 4) + ((s4 & 1) << 3)) = o4;
    }
  };
  // interleaved weight conversion: 4 float4 (wi|wo2) + up to 1 float4 (wo) per slot
  float4 cw[4]; float4 cwo;
  auto cvLoad = [&](int t) {
    int g0 = ((orig * 16 + t) * 512 + tid) * 4;     // 0..8M-4
    #pragma unroll
    for (int j = 0; j < 4; ++j) {
      int g = g0 + j;
      const float* src = (g < (4 << 20)) ? wi : wo2;
      int off = g & ((4 << 20) - 1);
      cw[j] = reinterpret_cast<const float4*>(src)[off];
    }
    int slot = (orig * 16 + t) * 512 + tid;         // 0..2M-1
    if (slot < (1 << 20)) cwo = reinterpret_cast<const float4*>(wo)[slot];
  };
  auto cvStore = [&](int t) {
    int g0 = ((orig * 16 + t) * 512 + tid) * 4;
    #pragma unroll
    for (int j = 0; j < 4; ++j) {
      union { ushort4 u; __hip_bfloat16 hh[4]; } o4;
      o4.hh[0] = __float2bfloat16(cw[j].x);
      o4.hh[1] = __float2bfloat16(cw[j].y);
      o4.hh[2] = __float2bfloat16(cw[j].z);
      o4.hh[3] = __float2bfloat16(cw[j].w);
      reinterpret_cast<ushort4*>(outw)[(4 << 20) + g0 + j] = o4.u;
    }
    int slot = (orig * 16 + t) * 512 + tid;
    if (slot < (1 << 20)) {
      union { ushort4 u; __hip_bfloat16 hh[4]; } o4;
      o4.hh[0] = __float2bfloat16(cwo.x);
      o4.hh[1] = __float2bfloat16(cwo.y);
      o4.hh[2] = __float2bfloat16(cwo.z);
      o4.hh[3] = __float2bfloat16(cwo.w);
      reinterpret_cast<ushort4*>(outw)[(3 << 20) + slot] = o4.u;
    }
  };

  f32x4 o[2][8] = {};
  float mrun[2][4], lrun[2][4];
  #pragma unroll
  for (int s = 0; s < 2; ++s)
    #pragma unroll
    for (int r = 0; r < 4; ++r) { mrun[s][r] = -1e30f; lrun[s][r] = 0.f; }
  const float scale = 0.08838834764831845f;         // 1/sqrt(128)

  stageK(0, 0);
  loadV(0);
  writeV(0);
  __syncthreads();

  int buf = 0;
  for (int t = 0; t < 16; ++t) {
    if (t + 1 < 16) { stageK(buf ^ 1, t + 1); loadV(t + 1); }
    cvLoad(t);                                      // fp32 weight chunk in flight

    float mv[4];
    #pragma unroll
    for (int j = 0; j < 4; ++j) mv[j] = mask[(size_t)b * kS + t * 64 + j * 16 + lr];

    #pragma unroll
    for (int s = 0; s < 2; ++s) {
      f32x4 sacc[4] = {};
      #pragma unroll
      for (int j = 0; j < 4; ++j) {
        int key = j * 16 + lr;
        #pragma unroll
        for (int kk = 0; kk < 4; ++kk) {
          short8 bfrag = *reinterpret_cast<const short8*>(
              Ks[buf] + key * 256 + (((kk * 4 + lg) ^ (key & 15)) * 16));
          sacc[j] = __builtin_amdgcn_mfma_f32_16x16x32_bf16(qf[s][kk], bfrag, sacc[j], 0, 0, 0);
        }
      }
      float sarr[4][4];
      #pragma unroll
      for (int j = 0; j < 4; ++j)
        #pragma unroll
        for (int r = 0; r < 4; ++r) sarr[j][r] = sacc[j][r] * scale + mv[j];
      #pragma unroll
      for (int r = 0; r < 4; ++r) {
        float tm = fmaxf(fmaxf(sarr[0][r], sarr[1][r]), fmaxf(sarr[2][r], sarr[3][r]));
        #pragma unroll
        for (int d = 1; d < 16; d <<= 1) tm = fmaxf(tm, __shfl_xor(tm, d));
        float mnew = fmaxf(mrun[s][r], tm);
        float alpha = __expf(mrun[s][r] - mnew);
        mrun[s][r] = mnew;
        float rs = 0.f;
        #pragma unroll
        for (int j = 0; j < 4; ++j) {
          float p = __expf(sarr[j][r] - mnew);
          sarr[j][r] = p;
          rs += p;
        }
        #pragma unroll
        for (int d = 1; d < 16; d <<= 1) rs += __shfl_xor(rs, d);
        lrun[s][r] = lrun[s][r] * alpha + rs;
        #pragma unroll
        for (int n = 0; n < 8; ++n) o[s][n][r] *= alpha;
      }
      #pragma unroll
      for (int r = 0; r < 4; ++r) {
        int qr = lg * 4 + r;
        #pragma unroll
        for (int j = 0; j < 4; ++j)
          *reinterpret_cast<__hip_bfloat16*>(
              Ps[w] + ((qr * 128 + (j * 16 + lr) * 2) ^ ((qr & 7) << 4))) =
              __float2bfloat16(sarr[j][r]);
      }
      #pragma unroll
      for (int kk2 = 0; kk2 < 2; ++kk2) {
        short8 pa = *reinterpret_cast<const short8*>(
            Ps[w] + ((lr * 128 + kk2 * 64 + lg * 16) ^ ((lr & 7) << 4)));
        #pragma unroll
        for (int n = 0; n < 8; ++n) {
          int hd = n * 16 + lr;
          short8 vb = *reinterpret_cast<const short8*>(
              Vt[buf] + hd * 128 + (((kk2 * 4 + lg) ^ (hd & 7)) * 16));
          o[s][n] = __builtin_amdgcn_mfma_f32_16x16x32_bf16(pa, vb, o[s][n], 0, 0, 0);
        }
      }
    }
    cvStore(t);                                     // convert + store (auto-waits cw)
    if (t + 1 < 16) writeV(buf ^ 1);
    __syncthreads();
    buf ^= 1;
  }

  #pragma unroll
  for (int s = 0; s < 2; ++s)
    #pragma unroll
    for (int r = 0; r < 4; ++r) {
      float inv = 1.0f / lrun[s][r];
      int srow = qp * 256 + s * 128 + w * 16 + lg * 4 + r;
      __hip_bfloat16* cp = ctx + (rb + srow) * kD + hc + lr;
      #pragma unroll
      for (int n = 0; n < 8; ++n) cp[n * 16] = __float2bfloat16(o[s][n][r] * inv);
    }
}

// -- LayerNorm over (bf16 p0 + bf16 p1 + f32 bias + bf16 res), one 2048-row/block --
// F32OUT=false: write bf16 only (LN1 -> a1b). F32OUT=true: write f32 (LN2 -> d_out).
template <bool F32OUT>
__global__ void ln_fuse(const __hip_bfloat16* __restrict__ p0,
                        const __hip_bfloat16* __restrict__ p1,
                        const float* __restrict__ bias,
                        const __hip_bfloat16* __restrict__ res,
                        const float* __restrict__ w, const float* __restrict__ b,
                        float* __restrict__ outf, __hip_bfloat16* __restrict__ outb) {
  const int row = blockIdx.x, tid = threadIdx.x;
  const size_t base = (size_t)row * kD;
  short8 a = reinterpret_cast<const short8*>(p0 + base)[tid];
  short8 c = reinterpret_cast<const short8*>(p1 + base)[tid];
  short8 rr = reinterpret_cast<const short8*>(res + base)[tid];
  float v[8];
  #pragma unroll
  for (int i = 0; i < 2; ++i) {
    int c4 = tid * 2 + i;
    float4 bs = reinterpret_cast<const float4*>(bias)[c4];
    v[i * 4 + 0] = b2f(a[i * 4 + 0]) + b2f(c[i * 4 + 0]) + b2f(rr[i * 4 + 0]) + bs.x;
    v[i * 4 + 1] = b2f(a[i * 4 + 1]) + b2f(c[i * 4 + 1]) + b2f(rr[i * 4 + 1]) + bs.y;
    v[i * 4 + 2] = b2f(a[i * 4 + 2]) + b2f(c[i * 4 + 2]) + b2f(rr[i * 4 + 2]) + bs.z;
    v[i * 4 + 3] = b2f(a[i * 4 + 3]) + b2f(c[i * 4 + 3]) + b2f(rr[i * 4 + 3]) + bs.w;
  }
  float s = 0.f;
  #pragma unroll
  for (int i = 0; i < 8; ++i) s += v[i];
  #pragma unroll
  for (int off = 32; off > 0; off >>= 1) s += __shfl_down(s, off);
  __shared__ float r1[4], r2[4];
  if ((tid & 63) == 0) r1[tid >> 6] = s;
  __syncthreads();
  float mean = (r1[0] + r1[1] + r1[2] + r1[3]) * (1.0f / kD);
  float qv = 0.f;
  #pragma unroll
  for (int i = 0; i < 8; ++i) { float d = v[i] - mean; qv += d * d; }
  #pragma unroll
  for (int off = 32; off > 0; off >>= 1) qv += __shfl_down(qv, off);
  if ((tid & 63) == 0) r2[tid >> 6] = qv;
  __syncthreads();
  float rstd = rsqrtf((r2[0] + r2[1] + r2[2] + r2[3]) * (1.0f / kD) + kEPS);
  #pragma unroll
  for (int i = 0; i < 8; ++i) {
    int col = tid * 8 + i;
    float ov = (v[i] - mean) * rstd * w[col] + b[col];
    if constexpr (F32OUT) outf[base + col] = ov;
    else                  outb[base + col] = __float2bfloat16(ov);
  }
}

// ---------------- launcher ----------------
extern "C" void kernel_launch(void* const* d_in, const int* in_sizes, int n_in,
                              void* d_out, int out_size, void* d_ws, size_t ws_size,
                              hipStream_t stream) {
  (void)in_sizes; (void)n_in; (void)out_size;
  if (ws_size < WS_NEED) return;
  const float* x    = (const float*)d_in[0];
  const float* mask = (const float*)d_in[1];
  const float* wq   = (const float*)d_in[2];
  const float* bq   = (const float*)d_in[3];
  const float* wk   = (const float*)d_in[4];
  const float* bk   = (const float*)d_in[5];
  const float* wv   = (const float*)d_in[6];
  const float* bv   = (const float*)d_in[7];
  const float* wo   = (const float*)d_in[8];
  const float* bo   = (const float*)d_in[9];
  const float* l1w  = (const float*)d_in[10];
  const float* l1b  = (const float*)d_in[11];
  const float* wi   = (const float*)d_in[12];
  const float* bi   = (const float*)d_in[13];
  const float* wo2  = (const float*)d_in[14];
  const float* bo2  = (const float*)d_in[15];
  const float* l2w  = (const float*)d_in[16];
  const float* l2b  = (const float*)d_in[17];

  char* ws = (char*)d_ws;
  __hip_bfloat16* wqb  = (__hip_bfloat16*)(ws + OFF_WQ);
  __hip_bfloat16* wob  = (__hip_bfloat16*)(ws + OFF_WO);
  __hip_bfloat16* wib  = (__hip_bfloat16*)(ws + OFF_WI);
  __hip_bfloat16* wo2b = (__hip_bfloat16*)(ws + OFF_WO2);
  __hip_bfloat16* xb   = (__hip_bfloat16*)(ws + OFF_XB);
  __hip_bfloat16* qkvb = (__hip_bfloat16*)(ws + OFF_Q);    // [4096][6144]
  __hip_bfloat16* hb   = (__hip_bfloat16*)(ws + OFF_H);
  __hip_bfloat16* ctxb = (__hip_bfloat16*)(ws + OFF_CTX);
  __hip_bfloat16* a1b  = (__hip_bfloat16*)(ws + OFF_A1B);  // bf16 attn_out (LN1 out)
  __hip_bfloat16* wp0 = (__hip_bfloat16*)(ws + OFF_Y2);            // Wo partial 0
  __hip_bfloat16* wp1 = (__hip_bfloat16*)(ws + OFF_Y2 + SZ_MD16);  // Wo partial 1
  __hip_bfloat16* fp0 = (__hip_bfloat16*)(ws + OFF_WQ);            // FFN2 partial 0
  __hip_bfloat16* fp1 = (__hip_bfloat16*)(ws + OFF_WQ + SZ_MD16);  // FFN2 partial 1
  float* bqkv = (float*)(ws + OFF_Y2);   // 24KB concat bias; dead before Wo partials

  // conversions: x + wq/wk/wv + bias concat (wo/wi/wo2 handled inside attn)
  cvt_all<<<2048, 256, 0, stream>>>(x, wq, wk, wv, bq, bk, bv, wqb, bqkv);

  dim3 blk(512);
  // fused QKV projection: M=4096, N=6144, K=2048 -> grid 384, row-major out
  gemm256<0><<<dim3(384), blk, 0, stream>>>(
      xb, wqb, bqkv, nullptr, nullptr, qkvb, kM, kDQKV, kD, kD);
  // attention (256 blocks, 2 q-tiles each) + wo/wi/wo2 conversion
  attn_fwd<<<dim3(256), dim3(512), 0, stream>>>(qkvb, mask, ctxb, wo, wi, wo2, wqb);
  // out proj, split-K x2 (grid 256), bf16 partials wp0,wp1; LN1 fuses +bo+xb -> a1b
  gemm256<3><<<dim3(256), blk, 0, stream>>>(
      ctxb, wob, nullptr, wp0, wp1, nullptr, kM, kD, kD, kD / 2);
  ln_fuse<false><<<kM, 256, 0, stream>>>(wp0, wp1, bo, xb, l1w, l1b, nullptr, a1b);
  // FFN1: grid 32*16 = 512, GELU epilogue
  gemm256<2><<<dim3(512), blk, 0, stream>>>(
      a1b, wib, bi, nullptr, nullptr, hb, kM, kF, kD, kD);
  // FFN2: split-K x2 (grid 256), bf16 partials fp0,fp1; LN2 fuses +bo2+a1b -> d_out
  gemm256<3><<<dim3(256), blk, 0, stream>>>(
      hb, wo2b, nullptr, fp0, fp1, nullptr, kM, kD, kF, kF / 2);
  ln_fuse<true><<<kM, 256, 0, stream>>>(fp0, fp1, bo2, a1b, l2w, l2b, (float*)d_out, nullptr);
}